// Round 7
// baseline (44.286 us; speedup 1.0000x reference)
//
#include <hip/hip_runtime.h>

#define NFEAT 2000
#define NMID  1998
#define BATCH 4096
#define PI_2  1.57079632679489662f

// Register-only MPS chain (left half only; zero LDS, zero barriers).
//
//   lane l of a 16-lane group owns component l of the bond vector v.
//   Step: v'[l] = sum_d v[d] * (c*M[d][0][l] + s*M[d][1][l])
//
//   v[d] is redistributed with a DPP butterfly allgather:
//     w[0]=v; for m in {1,2,4,8}: w[j+m] = dpp_xor_m(w[j]), j<m
//     => w[j] = v[l^j]   (induction: w[j+m](l) = w[j](l^m) = v[(l^m)^j] = v[l^(j+m)])
//   and paired with the XOR-staggered matrix load
//     A[2j+p] = cm[m][l^j][p][l]
//   so  sum_j w[j]*A[2j+p] = sum_j v[l^j]*M[l^j][p][l] = sum_d v[d]*M[d][p][l]
//   (l^j runs over all d). Exact reordering of the same dot product.
//
// EARLY EXIT: cores are 0.01-scale => ||v|| contracts ~25x/step; with FTZ v
// reaches exact fp32 zero after ~27 steps. Zero is absorbing (0 in -> 0 out,
// exactly), and out = <L, anything> = 0. Vote every step; exact for any
// input (non-decaying inputs run all 1998 steps through the same loop).

template<int CTRL>
__device__ __forceinline__ float dppf(float x) {
    int i = __float_as_int(x);
    return __int_as_float(__builtin_amdgcn_update_dpp(i, i, CTRL, 0xF, 0xF, false));
}
__device__ __forceinline__ float xor1f(float x){ return dppf<0xB1>(x); }               // quad_perm l^1
__device__ __forceinline__ float xor2f(float x){ return dppf<0x4E>(x); }               // quad_perm l^2
__device__ __forceinline__ float xor4f(float x){ return dppf<0x1B>(dppf<0x141>(x)); }  // (l^7) then (l^3)
__device__ __forceinline__ float xor8f(float x){ return dppf<0x141>(dppf<0x140>(x)); } // (l^15) then (l^7)

// staggered refill: A[k] = cm[mm][.] via precomputed per-lane offsets
#define RF(A, mm_) do {                                                     \
    const float* _pp = cm + (size_t)(mm_) * 512;                            \
    _Pragma("unroll")                                                       \
    for (int _k = 0; _k < 32; ++_k) A[_k] = _pp[vofs[_k]];                  \
    } while (0)

#define STEP(A, XV) do {                                                    \
    const float _th = (XV) * PI_2;                                          \
    const float _c = __cosf(_th), _s = __sinf(_th);                         \
    float w[16];                                                            \
    w[0] = v;                                                               \
    w[1] = xor1f(w[0]);                                                     \
    w[2] = xor2f(w[0]);  w[3] = xor2f(w[1]);                                \
    _Pragma("unroll")                                                       \
    for (int _j = 0; _j < 4; ++_j) w[4 + _j] = xor4f(w[_j]);                \
    _Pragma("unroll")                                                       \
    for (int _j = 0; _j < 8; ++_j) w[8 + _j] = xor8f(w[_j]);                \
    float _aA0 = w[0] * A[0],  _aB0 = w[0] * A[1];                          \
    float _aA1 = w[1] * A[2],  _aB1 = w[1] * A[3];                          \
    float _aA2 = w[2] * A[4],  _aB2 = w[2] * A[5];                          \
    float _aA3 = w[3] * A[6],  _aB3 = w[3] * A[7];                          \
    _Pragma("unroll")                                                       \
    for (int _j = 4; _j < 16; ++_j) {                                       \
        if ((_j & 3) == 0) { _aA0 = fmaf(w[_j], A[2*_j], _aA0); _aB0 = fmaf(w[_j], A[2*_j+1], _aB0); } \
        if ((_j & 3) == 1) { _aA1 = fmaf(w[_j], A[2*_j], _aA1); _aB1 = fmaf(w[_j], A[2*_j+1], _aB1); } \
        if ((_j & 3) == 2) { _aA2 = fmaf(w[_j], A[2*_j], _aA2); _aB2 = fmaf(w[_j], A[2*_j+1], _aB2); } \
        if ((_j & 3) == 3) { _aA3 = fmaf(w[_j], A[2*_j], _aA3); _aB3 = fmaf(w[_j], A[2*_j+1], _aB3); } \
    }                                                                       \
    const float _dA = (_aA0 + _aA1) + (_aA2 + _aA3);                        \
    const float _dB = (_aB0 + _aB1) + (_aB2 + _aB3);                        \
    v = fmaf(_c, _dA, _s * _dB);                                            \
    } while (0)

__global__ __launch_bounds__(256, 1)
void mps_dpp_kernel(const float* __restrict__ x,  const float* __restrict__ cf,
                    const float* __restrict__ cm, const float* __restrict__ cl,
                    float* __restrict__ out)
{
    // flush f32 denormals (MODE.FP_DENORM bits [5:4] = 0): decay hits exact 0
    // at the normal floor (~1.2e-38) instead of crawling through denormals
    asm volatile("s_setreg_imm32_b32 hwreg(HW_REG_MODE, 4, 2), 0");

    const int tid = threadIdx.x;
    const int g   = tid >> 4;      // sample slot 0..15
    const int l   = tid & 15;      // bond lane 0..15
    const int b   = blockIdx.x * 16 + g;
    const size_t xrow = (size_t)b * NFEAT;

    // per-lane staggered offsets: vofs[2j+p] = (l^j)*32 + p*16 + l  (floats)
    int vofs[32];
    #pragma unroll
    for (int j = 0; j < 16; ++j) {
        vofs[2 * j]     = ((l ^ j) << 5) + l;
        vofs[2 * j + 1] = ((l ^ j) << 5) + 16 + l;
    }

    // ---- v0 from core_first, feature 0 ----
    float v;
    {
        const float th = x[xrow] * PI_2;
        v = fmaf(__sinf(th), cf[16 + l], __cosf(th) * cf[l]);
    }

    // ---- prologue: matrices for steps 0..2, x for steps 0..2 ----
    float A0[32], A1[32], A2[32];
    RF(A0, 0);
    RF(A1, 1);
    RF(A2, 2);
    float xq0 = x[xrow + 1];
    float xq1 = x[xrow + 2];
    float xq2 = x[xrow + 3];

    // ---- main loop: 666 iterations x 3 steps = 1998 steps ----
    for (int m = 0; m < NMID; m += 3) {
        // prefetch next triple's x (clamped; clamp only matters on last iter)
        const int xi = (m + 6 <= NFEAT - 1) ? m + 4 : NFEAT - 3;
        const float nx0 = x[xrow + xi];
        const float nx1 = x[xrow + xi + 1];
        const float nx2 = x[xrow + xi + 2];
        // refill targets (clamped; clamped loads are never consumed)
        const int r0 = (m + 3 < NMID) ? m + 3 : NMID - 1;
        const int r1 = (m + 4 < NMID) ? m + 4 : NMID - 1;
        const int r2 = (m + 5 < NMID) ? m + 5 : NMID - 1;

        STEP(A0, xq0);
        if (__all(v == 0.0f)) break;
        RF(A0, r0);
        STEP(A1, xq1);
        if (__all(v == 0.0f)) break;
        RF(A1, r1);
        STEP(A2, xq2);
        if (__all(v == 0.0f)) break;
        RF(A2, r2);

        xq0 = nx0; xq1 = nx1; xq2 = nx2;
    }

    // ---- epilogue: out[b] = sum_l v[l] * (c*cl[l][0] + s*cl[l][1]) ----
    {
        const float th = x[xrow + NFEAT - 1] * PI_2;
        float p = v * fmaf(__sinf(th), cl[2 * l + 1], __cosf(th) * cl[2 * l]);
        p += __shfl_xor(p, 1);
        p += __shfl_xor(p, 2);
        p += __shfl_xor(p, 4);
        p += __shfl_xor(p, 8);
        if (l == 0) out[b] = p;
    }
}

extern "C" void kernel_launch(void* const* d_in, const int* in_sizes, int n_in,
                              void* d_out, int out_size, void* d_ws, size_t ws_size,
                              hipStream_t stream) {
    const float* x  = (const float*)d_in[0];
    const float* cf = (const float*)d_in[1];
    const float* cm = (const float*)d_in[2];
    const float* cl = (const float*)d_in[3];
    float* out = (float*)d_out;
    hipLaunchKernelGGL(mps_dpp_kernel, dim3(BATCH / 16), dim3(256), 0, stream,
                       x, cf, cm, cl, out);
}

// Round 8
// 17.984 us; speedup vs baseline: 2.4625x; 2.4625x over previous
//
#include <hip/hip_runtime.h>

#define NFEAT 2000
#define NMID  1998
#define BATCH 4096
#define PI_2  1.57079632679489662f
#define KREP  40     // cores repacked into LDS (early exit expected ~step 30)

// Register-resident MPS chain with DPP-butterfly v-redistribution.
//
//   lane l of a 16-lane group owns component l of the bond vector v.
//   Step: v'[l] = sum_d v[d] * (c*M[d][0][l] + s*M[d][1][l])
//   Butterfly allgather: w[0]=v; for m in {1,2,4,8}: w[j+m](l) = w[j](l^m)
//     => w[j](l) = v[l^j]; paired with A[2j+p] = M[l^j][p][l]:
//     sum_j w[j]*A[2j+p] = sum_d v[d]*M[d][p][l]  (l^j is a bijection) — exact.
//
//   Matrix fragments come from an LDS repack lrep[m][j][l][p] = cm[m][l^j][p][l]:
//   per step 16x ds_read_b64, lane l at float offset j*32+l*2 -> banks {2l,2l+1},
//   all 32 banks covered once per 16-lane group, groups broadcast: conflict-free.
//
// EARLY EXIT: cores are 0.01-scale => ||v|| contracts ~25x/step; with FTZ v
// reaches exact fp32 zero ~step 30. Zero is absorbing (0 in -> 0 out exactly;
// final join gives exact 0), so once the wave's 4 samples are all-zero the
// rest of the chain is provably a no-op. Vote every step — exact for any
// input; non-decaying inputs continue past core KREP via chain_tail below.

template<int CTRL>
__device__ __forceinline__ float dppf(float x) {
    int i = __float_as_int(x);
    return __int_as_float(__builtin_amdgcn_update_dpp(i, i, CTRL, 0xF, 0xF, false));
}
__device__ __forceinline__ float xor1f(float x){ return dppf<0xB1>(x); }               // quad_perm(1,0,3,2): l^1
__device__ __forceinline__ float xor2f(float x){ return dppf<0x4E>(x); }               // quad_perm(2,3,0,1): l^2
__device__ __forceinline__ float xor4f(float x){ return dppf<0x1B>(dppf<0x141>(x)); }  // (l^7) then (l^3) = l^4
__device__ __forceinline__ float xor8f(float x){ return dppf<0x141>(dppf<0x140>(x)); } // (l^15) then (l^7) = l^8

#define STEP(A, XV) do {                                                    \
    const float _th = (XV) * PI_2;                                          \
    const float _c = __cosf(_th), _s = __sinf(_th);                         \
    float w[16];                                                            \
    w[0] = v;                                                               \
    w[1] = xor1f(w[0]);                                                     \
    w[2] = xor2f(w[0]);  w[3] = xor2f(w[1]);                                \
    _Pragma("unroll")                                                       \
    for (int _j = 0; _j < 4; ++_j) w[4 + _j] = xor4f(w[_j]);                \
    _Pragma("unroll")                                                       \
    for (int _j = 0; _j < 8; ++_j) w[8 + _j] = xor8f(w[_j]);                \
    float _aA0 = w[0] * A[0],  _aB0 = w[0] * A[1];                          \
    float _aA1 = w[1] * A[2],  _aB1 = w[1] * A[3];                          \
    float _aA2 = w[2] * A[4],  _aB2 = w[2] * A[5];                          \
    float _aA3 = w[3] * A[6],  _aB3 = w[3] * A[7];                          \
    _Pragma("unroll")                                                       \
    for (int _j = 4; _j < 16; ++_j) {                                       \
        if ((_j & 3) == 0) { _aA0 = fmaf(w[_j], A[2*_j], _aA0); _aB0 = fmaf(w[_j], A[2*_j+1], _aB0); } \
        if ((_j & 3) == 1) { _aA1 = fmaf(w[_j], A[2*_j], _aA1); _aB1 = fmaf(w[_j], A[2*_j+1], _aB1); } \
        if ((_j & 3) == 2) { _aA2 = fmaf(w[_j], A[2*_j], _aA2); _aB2 = fmaf(w[_j], A[2*_j+1], _aB2); } \
        if ((_j & 3) == 3) { _aA3 = fmaf(w[_j], A[2*_j], _aA3); _aB3 = fmaf(w[_j], A[2*_j+1], _aB3); } \
    }                                                                       \
    const float _dA = (_aA0 + _aA1) + (_aA2 + _aA3);                        \
    const float _dB = (_aB0 + _aB1) + (_aB2 + _aB3);                        \
    v = fmaf(_c, _dA, _s * _dB);                                            \
    } while (0)

// prefetch core mm_ from the LDS repack: 16x ds_read_b64, conflict-free
#define PF(A, mm_) do {                                                     \
    const float2* _q = (const float2*)(lrep + ((mm_) << 9) + (l << 1));     \
    _Pragma("unroll")                                                       \
    for (int _j = 0; _j < 16; ++_j) {                                       \
        const float2 _t = _q[_j * 16];                                      \
        A[2 * _j]     = _t.x;                                               \
        A[2 * _j + 1] = _t.y;                                               \
    } } while (0)

// Correctness-only tail past core KREP (never taken for decaying inputs).
// noinline: its register/spill behavior stays out of the hot loop.
__device__ __noinline__ float chain_tail(float v, int m0, const float* __restrict__ x,
                                         const float* __restrict__ cm, int l, size_t xrow)
{
    for (int m = m0; m < NMID; ++m) {
        const float xv = x[xrow + m + 1];
        float A[32];
        #pragma unroll
        for (int j = 0; j < 16; ++j) {
            const float* p = cm + ((size_t)m << 9) + ((l ^ j) << 5) + l;
            A[2 * j]     = p[0];
            A[2 * j + 1] = p[16];
        }
        STEP(A, xv);
        if (__all(v == 0.0f)) break;
    }
    return v;
}

__global__ __launch_bounds__(256, 1)
void mps_bfly_kernel(const float* __restrict__ x,  const float* __restrict__ cf,
                     const float* __restrict__ cm, const float* __restrict__ cl,
                     float* __restrict__ out)
{
    // flush f32 denormals (MODE.FP_DENORM bits [5:4] = 0): decay reaches exact
    // zero at the normal floor instead of crawling through denormals
    asm volatile("s_setreg_imm32_b32 hwreg(HW_REG_MODE, 4, 2), 0");

    __shared__ float lrep[KREP * 512];   // 81920 B

    const int tid = threadIdx.x;
    const int g   = tid >> 4;      // sample slot 0..15
    const int l   = tid & 15;      // bond lane 0..15
    const int b   = blockIdx.x * 16 + g;
    const size_t xrow = (size_t)b * NFEAT;

    // ---- repack cores 0..KREP-1 into LDS: lrep[m][j][l][p] = cm[m][l^j][p][l] ----
    // src idx = m*512 + d*32 + p*16 + e  ->  dst = m*512 + (d^e)*32 + e*2 + p
    {
        const float4* src = (const float4*)cm;
        #pragma unroll
        for (int k = 0; k < (KREP * 128) / 256; ++k) {   // 20 float4 per thread
            const int f = tid + 256 * k;
            const float4 val = src[f];
            const int i0 = 4 * f;
            #pragma unroll
            for (int c = 0; c < 4; ++c) {
                const int idx = i0 + c;
                const int m = idx >> 9, r = idx & 511;
                const int d = r >> 5, p = (r >> 4) & 1, e = r & 15;
                lrep[(m << 9) + ((d ^ e) << 5) + (e << 1) + p] =
                    (c == 0) ? val.x : (c == 1) ? val.y : (c == 2) ? val.z : val.w;
            }
        }
    }

    // ---- v0 from core_first, feature 0 (overlaps repack writes) ----
    float v;
    {
        const float th = x[xrow] * PI_2;
        v = fmaf(__sinf(th), cf[16 + l], __cosf(th) * cf[l]);
    }

    __syncthreads();

    // ---- pipeline prologue ----
    float A0[32], A1[32];
    PF(A0, 0);
    PF(A1, 1);
    float xa = x[xrow + 1];
    float xb = x[xrow + 2];

    int  mm   = 0;
    bool dead = false;
    for (; mm + 1 < KREP; mm += 2) {
        STEP(A0, xa);                       // step mm
        if (__all(v == 0.0f)) { dead = true; break; }
        { const int rn = (mm + 2 < KREP) ? mm + 2 : KREP - 1; PF(A0, rn); }
        xa = x[xrow + mm + 3];
        STEP(A1, xb);                       // step mm+1
        if (__all(v == 0.0f)) { dead = true; break; }
        { const int rn = (mm + 3 < KREP) ? mm + 3 : KREP - 1; PF(A1, rn); }
        xb = x[xrow + mm + 4];
    }
    if (!dead)                              // mm == KREP here; continue from cm
        v = chain_tail(v, KREP, x, cm, l, xrow);

    // ---- epilogue: out[b] = sum_l v[l] * (c*cl[l][0] + s*cl[l][1]) ----
    {
        const float th = x[xrow + NFEAT - 1] * PI_2;
        float p = v * fmaf(__sinf(th), cl[2 * l + 1], __cosf(th) * cl[2 * l]);
        p += __shfl_xor(p, 1);
        p += __shfl_xor(p, 2);
        p += __shfl_xor(p, 4);
        p += __shfl_xor(p, 8);
        if (l == 0) out[b] = p;
    }
}

extern "C" void kernel_launch(void* const* d_in, const int* in_sizes, int n_in,
                              void* d_out, int out_size, void* d_ws, size_t ws_size,
                              hipStream_t stream) {
    const float* x  = (const float*)d_in[0];
    const float* cf = (const float*)d_in[1];
    const float* cm = (const float*)d_in[2];
    const float* cl = (const float*)d_in[3];
    float* out = (float*)d_out;
    hipLaunchKernelGGL(mps_bfly_kernel, dim3(BATCH / 16), dim3(256), 0, stream,
                       x, cf, cm, cl, out);
}

// Round 9
// 15.925 us; speedup vs baseline: 2.7808x; 1.1293x over previous
//
#include <hip/hip_runtime.h>

#define NFEAT 2000
#define NMID  1998
#define BATCH 4096
#define PI_2  1.57079632679489662f

// Column-decomposition MPS chain, left-to-right only.
//   lane l of a 16-lane group owns component l of the bond vector.
//   v'[l] = sum_d v[d] * (c*M[d][0][l] + s*M[d][1][l])
// For fixed (d,p) the 16 lanes read 64 contiguous bytes of cm -> coalesced,
// no repacking needed. Full-v redistribution goes through a tiny LDS buffer;
// each group lives inside one wave, so DS ops are wave-ordered (no barriers).
//
// EARLY EXIT: cores are 0.01-scale, so ||v|| contracts ~25x per step and v
// underflows to exact fp32 zero after ~35 steps. Zero is absorbing (0-vector
// in, 0-vector out, exactly), so once the wave's 4 samples are all-zero the
// remaining chain is provably a no-op. Vote every 2 steps (still exact).
//
// Session result: 471us (naive bidirectional LDS-tiled) -> 15.8us via
// pair-products, column decomposition, and the exact-absorption early exit.
// Remaining wall clock is ~12us fixed graph-replay overhead + ~4us kernel;
// the kernel is launch-overhead-floored, not memory- or compute-bound
// (FETCH ~0.8MB, zero bank conflicts, VALUBusy ~10%, dispatch invisible
// next to the harness's own 40us poison fills).

#define REFILL(A, mm) do {                                                  \
    const float* _p = cm + (size_t)(mm) * 512 + l;                          \
    _Pragma("unroll")                                                       \
    for (int _d = 0; _d < 16; ++_d) {                                       \
        A[_d]      = _p[_d * 32];                                           \
        A[16 + _d] = _p[_d * 32 + 16];                                      \
    } } while (0)

#define DOT16(R, A, OFF) do {                                               \
    R = 0.f;                                                                \
    _Pragma("unroll")                                                       \
    for (int _j = 0; _j < 4; ++_j) {                                        \
        R = fmaf(W[_j].x, A[OFF + 4 * _j + 0], R);                          \
        R = fmaf(W[_j].y, A[OFF + 4 * _j + 1], R);                          \
        R = fmaf(W[_j].z, A[OFF + 4 * _j + 2], R);                          \
        R = fmaf(W[_j].w, A[OFF + 4 * _j + 3], R);                          \
    } } while (0)

#define STEP(A, XV) do {                                                    \
    const float _th = (XV) * PI_2;                                          \
    const float _c = __cosf(_th), _s = __sinf(_th);                         \
    float _dA, _dB;                                                         \
    DOT16(_dA, A, 0);                                                       \
    DOT16(_dB, A, 16);                                                      \
    v = fmaf(_c, _dA, _s * _dB);                                            \
    } while (0)

#define EXCH() do {                                                         \
    vx[g][l] = v;                                                           \
    W[0] = *(const float4*)&vx[g][0];                                       \
    W[1] = *(const float4*)&vx[g][4];                                       \
    W[2] = *(const float4*)&vx[g][8];                                       \
    W[3] = *(const float4*)&vx[g][12];                                      \
    } while (0)

__global__ __launch_bounds__(256, 1)
void mps_col_kernel(const float* __restrict__ x,  const float* __restrict__ cf,
                    const float* __restrict__ cm, const float* __restrict__ cl,
                    float* __restrict__ out)
{
    __shared__ float vx[16][20];   // padded: group exchange buffer, 1.25 KB

    const int tid = threadIdx.x;
    const int g   = tid >> 4;      // sample slot 0..15
    const int l   = tid & 15;      // bond lane 0..15
    const int b   = blockIdx.x * 16 + g;
    const size_t xrow = (size_t)b * NFEAT;

    // ---- v0 from core_first, feature 0 ----
    float v;
    {
        const float th = x[xrow] * PI_2;
        v = fmaf(__sinf(th), cf[16 + l], __cosf(th) * cf[l]);
    }

    float4 W[4];
    EXCH();                        // distribute v0 to the group

    // ---- pipeline prologue: columns for steps 0 and 1, features 1 and 2 ----
    float a0[32], a1[32];
    REFILL(a0, 0);
    REFILL(a1, 1);
    float xa = x[xrow + 1];
    float xb = x[xrow + 2];

    bool dead = false;
    for (int m = 0; m < NMID - 2; m += 2) {
        STEP(a0, xa);              // step m
        EXCH();
        REFILL(a0, m + 2);         // refill one full step ahead of use
        xa = x[xrow + m + 3];
        STEP(a1, xb);              // step m+1
        if (__all(v == 0.0f)) { dead = true; break; }
        EXCH();
        REFILL(a1, m + 3);
        xb = x[xrow + m + 4];
    }
    if (!dead) {                   // tail: steps 1996, 1997 (already in a0/a1)
        STEP(a0, xa);
        EXCH();
        STEP(a1, xb);
    }

    // ---- epilogue: out[b] = sum_l v[l] * (c*cl[l][0] + s*cl[l][1]) ----
    {
        const float th = x[xrow + NFEAT - 1] * PI_2;
        float p = v * fmaf(__sinf(th), cl[2 * l + 1], __cosf(th) * cl[2 * l]);
        p += __shfl_xor(p, 1);
        p += __shfl_xor(p, 2);
        p += __shfl_xor(p, 4);
        p += __shfl_xor(p, 8);
        if (l == 0) out[b] = p;
    }
}

extern "C" void kernel_launch(void* const* d_in, const int* in_sizes, int n_in,
                              void* d_out, int out_size, void* d_ws, size_t ws_size,
                              hipStream_t stream) {
    const float* x  = (const float*)d_in[0];
    const float* cf = (const float*)d_in[1];
    const float* cm = (const float*)d_in[2];
    const float* cl = (const float*)d_in[3];
    float* out = (float*)d_out;
    hipLaunchKernelGGL(mps_col_kernel, dim3(BATCH / 16), dim3(256), 0, stream,
                       x, cf, cm, cl, out);
}